// Round 12
// baseline (1801.201 us; speedup 1.0000x reference)
//
#include <hip/hip_runtime.h>
#include <hip/hip_bf16.h>
#include <math.h>

constexpr int cB = 8, cT = 510, cNH = 12, cEX = 768, cVOC = 256, cNBLK = 11, cHD = 64;
constexpr int cMB = 512;         // padded rows per batch
constexpr int cMP = 4096;        // total padded rows (8*512)
constexpr int cQKV = 3 * cEX;    // 2304

typedef __attribute__((ext_vector_type(8))) short bf16x8;
typedef __attribute__((ext_vector_type(4))) float f32x4;
typedef __attribute__((ext_vector_type(16))) float f32x16;
using bf16 = __hip_bfloat16;

__device__ inline void gload16(const void* g, void* l) {
    __builtin_amdgcn_global_load_lds((const __attribute__((address_space(1))) unsigned int*)g,
                                     (__attribute__((address_space(3))) unsigned int*)l, 16, 0, 0);
}
__device__ inline short f2bs(float f) {
    bf16 b = __float2bfloat16(f);
    return *reinterpret_cast<short*>(&b);
}
__device__ inline float bs2f(unsigned short s) {
    unsigned int u = ((unsigned int)s) << 16;
    float f;
    __builtin_memcpy(&f, &u, 4);
    return f;
}

// ---------------- embedding: rows b*512+t, zero pads; x is bf16 ----------------
__global__ __launch_bounds__(256) void embed_kernel(
    const int* __restrict__ idx, const float* __restrict__ lin_w,
    const float* __restrict__ lin_b, short* __restrict__ x)
{
    int row = blockIdx.x;
    int b = row >> 9, t = row & 511;
    short* xr = x + (size_t)row * cEX;
    if (t >= cT) {
        for (int j = threadIdx.x; j < cEX; j += 256) xr[j] = 0;
        return;
    }
    int tok = idx[b * cT + t] & 1;
    const float* wt = lin_w + (size_t)tok * cEX;
    const float* wp = lin_w + (size_t)(2 + t) * cEX;
    for (int j = threadIdx.x; j < cEX; j += 256) {
        float val = wt[j] + wp[j] + lin_b[j];
        xr[j] = f2bs(fmaxf(val, 0.0f));
    }
}

// ---------------- layernorm: one row per wave, bf16 in -> bf16 out ----------------
__global__ __launch_bounds__(256) void ln_wave(
    const short* __restrict__ in, const float* __restrict__ s,
    const float* __restrict__ bsh, short* __restrict__ out)
{
    const int wid = threadIdx.x >> 6, lane = threadIdx.x & 63;
    const int row = blockIdx.x * 4 + wid;
    const short* xr = in + (size_t)row * cEX;
    float v[12];
    float sum = 0.f, sq = 0.f;
#pragma unroll
    for (int p = 0; p < 3; ++p) {
        ushort4 raw = *(const ushort4*)&xr[p * 256 + lane * 4];
        v[p * 4 + 0] = bs2f(raw.x); v[p * 4 + 1] = bs2f(raw.y);
        v[p * 4 + 2] = bs2f(raw.z); v[p * 4 + 3] = bs2f(raw.w);
#pragma unroll
        for (int q = 0; q < 4; ++q) { sum += v[p * 4 + q]; sq += v[p * 4 + q] * v[p * 4 + q]; }
    }
#pragma unroll
    for (int off = 1; off < 64; off <<= 1) {
        sum += __shfl_xor(sum, off, 64);
        sq  += __shfl_xor(sq, off, 64);
    }
    float mean = sum * (1.0f / cEX);
    float var = sq * (1.0f / cEX) - mean * mean;
    float rstd = rsqrtf(var + 1e-5f);
    short* outr = out + (size_t)row * cEX;
#pragma unroll
    for (int p = 0; p < 3; ++p) {
        int c = p * 256 + lane * 4;
        float4 sv = *(const float4*)&s[c];
        float4 bv = *(const float4*)&bsh[c];
        short4 pk;
        pk.x = f2bs((v[p * 4 + 0] - mean) * rstd * sv.x + bv.x);
        pk.y = f2bs((v[p * 4 + 1] - mean) * rstd * sv.y + bv.y);
        pk.z = f2bs((v[p * 4 + 2] - mean) * rstd * sv.z + bv.z);
        pk.w = f2bs((v[p * 4 + 3] - mean) * rstd * sv.w + bv.w);
        *(short4*)&outr[c] = pk;
    }
}

// ---------------- weight transpose + fp32->bf16: W[K][N] -> WT[N][K] ----------------
__global__ __launch_bounds__(256) void transpose_w(
    const float* __restrict__ W, bf16* __restrict__ WT,
    int K, int N, size_t w_stride, size_t wt_stride, int wt_row_off)
{
    __shared__ float t[32][33];
    const float* Wb = W + (size_t)blockIdx.z * w_stride;
    bf16* WTb = WT + (size_t)blockIdx.z * wt_stride;
    int n0 = blockIdx.x * 32, k0 = blockIdx.y * 32;
    int c = threadIdx.x & 31, ty = threadIdx.x >> 5;
#pragma unroll
    for (int it = 0; it < 4; ++it) {
        int r = ty + it * 8;
        t[r][c] = Wb[(size_t)(k0 + r) * N + n0 + c];
    }
    __syncthreads();
#pragma unroll
    for (int it = 0; it < 4; ++it) {
        int a = ty + it * 8;
        WTb[(size_t)(wt_row_off + n0 + a) * K + k0 + c] = __float2bfloat16(t[c][a]);
    }
}

// ---------------- fused q/k/v weight transpose: z = blk*3 + which ----------------
__global__ __launch_bounds__(256) void transpose_qkv(
    const float* __restrict__ qw, const float* __restrict__ kw,
    const float* __restrict__ vw, bf16* __restrict__ WT)
{
    __shared__ float t[32][33];
    int z = blockIdx.z;
    int blk = z / 3, which = z - blk * 3;
    const float* Wb = (which == 0 ? qw : which == 1 ? kw : vw) + (size_t)blk * cEX * cEX;
    bf16* WTb = WT + (size_t)blk * cQKV * cEX + (size_t)which * cEX * cEX;
    int n0 = blockIdx.x * 32, k0 = blockIdx.y * 32;
    int c = threadIdx.x & 31, ty = threadIdx.x >> 5;
#pragma unroll
    for (int it = 0; it < 4; ++it) {
        int r = ty + it * 8;
        t[r][c] = Wb[(size_t)(k0 + r) * cEX + n0 + c];
    }
    __syncthreads();
#pragma unroll
    for (int it = 0; it < 4; ++it) {
        int a = ty + it * 8;
        WTb[(size_t)(n0 + a) * cEX + k0 + c] = __float2bfloat16(t[c][a]);
    }
}

// ---------------- concat q/k/v biases ----------------
__global__ __launch_bounds__(256) void concat_bias(
    const float* __restrict__ qb, const float* __restrict__ kb,
    const float* __restrict__ vb, float* __restrict__ qkvb)
{
    int i = blockIdx.x * 256 + threadIdx.x;
    if (i >= cNBLK * cQKV) return;
    int blk = i / cQKV, c = i - blk * cQKV;
    const float* src; int cc = c;
    if (c < cEX)            { src = qb; }
    else if (c < 2 * cEX)   { src = kb; cc = c - cEX; }
    else                    { src = vb; cc = c - 2 * cEX; }
    qkvb[i] = src[(size_t)blk * cEX + cc];
}

// ---------------- 32x32x16 MFMA GEMM: 128x128 tile, 2x2 waves of 64x64 ----------------
// Same proven sync skeleton as gemm_db (r5-r8): vmcnt(8)+barrier publishes tile t,
// lgkmcnt(0)+barrier certifies reads before re-stage, stage 2-ahead, ks-phase split.
// A/B frag: lane holds row=lane&31, k=(lane>>5)*8+j (one b128). C/D [m74/m101]:
// col=lane&31, row=(reg&3)+8*(reg>>2)+4*(lane>>5).
template<bool RELU, bool VT>
__global__ __launch_bounds__(256) void gemm32(
    const short* __restrict__ A, const short* __restrict__ BT,
    const float* __restrict__ bias, void* __restrict__ Cout,
    short* __restrict__ vTr, int K, int N)
{
    constexpr int BM = 128, BN = 128;
    constexpr int TS = (BM + BN) * 64;          // shorts per K-tile buffer
    __shared__ short lds[2 * TS];
    const int tid = threadIdx.x;
    const int lane = tid & 63, wid = tid >> 6;
    const int wm = wid >> 1, wn = wid & 1;
    const int bm = blockIdx.y * BM, bn = blockIdx.x * BN;
    const int l32 = lane & 31, kh = lane >> 5;   // kh = k-half within 16

    f32x16 acc[2][2];
#pragma unroll
    for (int i = 0; i < 2; ++i)
#pragma unroll
        for (int j = 0; j < 2; ++j)
            acc[i][j] = f32x16{0.f,0.f,0.f,0.f,0.f,0.f,0.f,0.f,
                               0.f,0.f,0.f,0.f,0.f,0.f,0.f,0.f};

    auto stage = [&](int kt, int buf) {
        short* la = &lds[buf * TS];
        short* lb = la + BM * 64;
#pragma unroll
        for (int i = 0; i < 4; ++i) {
            int s = i * 256 + tid;
            int r = s >> 3, c = s & 7;
            gload16(A + (size_t)(bm + r) * K + kt * 64 + (c ^ (r & 7)) * 8,
                    (char*)la + (size_t)(i * 256 + wid * 64) * 16);
        }
#pragma unroll
        for (int i = 0; i < 4; ++i) {
            int s = i * 256 + tid;
            int r = s >> 3, c = s & 7;
            gload16(BT + (size_t)(bn + r) * K + kt * 64 + (c ^ (r & 7)) * 8,
                    (char*)lb + (size_t)(i * 256 + wid * 64) * 16);
        }
    };

    const int nkt = K >> 6;
    stage(0, 0);
    stage(1, 1);

    for (int t = 0; t < nkt; ++t) {
        if (t + 1 < nkt) asm volatile("s_waitcnt vmcnt(8)" ::: "memory");
        else             asm volatile("s_waitcnt vmcnt(0)" ::: "memory");
        __builtin_amdgcn_s_barrier();

        const short* la = &lds[(t & 1) * TS];
        const short* lb = la + BM * 64;

        // ---- phase 1: ksteps 0,1 ----
        bf16x8 af0[2][2], bf0[2][2];   // [mi/ni][kstep]
#pragma unroll
        for (int mi = 0; mi < 2; ++mi) {
            int row = (wm * 2 + mi) * 32 + l32;
#pragma unroll
            for (int ks = 0; ks < 2; ++ks)
                af0[mi][ks] = *(const bf16x8*)&la[row * 64 + ((ks * 2 + kh) ^ (row & 7)) * 8];
        }
#pragma unroll
        for (int ni = 0; ni < 2; ++ni) {
            int row = (wn * 2 + ni) * 32 + l32;
#pragma unroll
            for (int ks = 0; ks < 2; ++ks)
                bf0[ni][ks] = *(const bf16x8*)&lb[row * 64 + ((ks * 2 + kh) ^ (row & 7)) * 8];
        }
        __builtin_amdgcn_s_setprio(1);
#pragma unroll
        for (int ks = 0; ks < 2; ++ks)
#pragma unroll
            for (int mi = 0; mi < 2; ++mi)
#pragma unroll
                for (int ni = 0; ni < 2; ++ni)
                    acc[mi][ni] = __builtin_amdgcn_mfma_f32_32x32x16_bf16(
                        af0[mi][ks], bf0[ni][ks], acc[mi][ni], 0, 0, 0);
        __builtin_amdgcn_s_setprio(0);

        // ---- phase 2: ksteps 2,3 reads, free buffer, stage, compute ----
        bf16x8 af1[2][2], bf1[2][2];
#pragma unroll
        for (int mi = 0; mi < 2; ++mi) {
            int row = (wm * 2 + mi) * 32 + l32;
#pragma unroll
            for (int ks = 0; ks < 2; ++ks)
                af1[mi][ks] = *(const bf16x8*)&la[row * 64 + (((ks + 2) * 2 + kh) ^ (row & 7)) * 8];
        }
#pragma unroll
        for (int ni = 0; ni < 2; ++ni) {
            int row = (wn * 2 + ni) * 32 + l32;
#pragma unroll
            for (int ks = 0; ks < 2; ++ks)
                bf1[ni][ks] = *(const bf16x8*)&lb[row * 64 + (((ks + 2) * 2 + kh) ^ (row & 7)) * 8];
        }
        asm volatile("s_waitcnt lgkmcnt(0)" ::: "memory");
        __builtin_amdgcn_s_barrier();
        if (t + 2 < nkt) stage(t + 2, t & 1);
        __builtin_amdgcn_s_setprio(1);
#pragma unroll
        for (int ks = 0; ks < 2; ++ks)
#pragma unroll
            for (int mi = 0; mi < 2; ++mi)
#pragma unroll
                for (int ni = 0; ni < 2; ++ni)
                    acc[mi][ni] = __builtin_amdgcn_mfma_f32_32x32x16_bf16(
                        af1[mi][ks], bf1[ni][ks], acc[mi][ni], 0, 0, 0);
        __builtin_amdgcn_s_setprio(0);
    }

    // epilogue: col=lane&31, row=(reg&3)+8*(reg>>2)+4*(lane>>5)
#pragma unroll
    for (int mi = 0; mi < 2; ++mi) {
#pragma unroll
        for (int ni = 0; ni < 2; ++ni) {
            int col = bn + (wn * 2 + ni) * 32 + l32;
            float bv = bias[col];
            int rbase = bm + (wm * 2 + mi) * 32 + 4 * kh;
            if (VT && col >= 2 * cEX) {
#pragma unroll
                for (int g = 0; g < 4; ++g) {
                    int r0 = rbase + 8 * g;
                    short4 pk;
                    pk.x = f2bs(acc[mi][ni][g * 4 + 0] + bv);
                    pk.y = f2bs(acc[mi][ni][g * 4 + 1] + bv);
                    pk.z = f2bs(acc[mi][ni][g * 4 + 2] + bv);
                    pk.w = f2bs(acc[mi][ni][g * 4 + 3] + bv);
                    *(short4*)&vTr[(size_t)(col - 2 * cEX) * cMP + r0] = pk;
                }
            } else {
#pragma unroll
                for (int g = 0; g < 4; ++g)
#pragma unroll
                    for (int j = 0; j < 4; ++j) {
                        int row = rbase + 8 * g + j;
                        float v = acc[mi][ni][g * 4 + j] + bv;
                        if (RELU) v = fmaxf(v, 0.0f);
                        ((bf16*)Cout)[(size_t)row * N + col] = __float2bfloat16(v);
                    }
            }
        }
    }
}

// ---------------- 16x16 MFMA GEMM (eproj/m2): 2x2 waves, exact grids ----------------
template<int FM, int FN, bool RELU, bool RESID, bool OUTBF16>
__global__ __launch_bounds__(256) void gemm_db(
    const short* __restrict__ A, const short* __restrict__ BT,
    const float* __restrict__ bias, const short* __restrict__ resid,
    void* __restrict__ Cout, int K, int N)
{
    constexpr int BM = FM * 32, BN = FN * 32;
    constexpr int TS = (BM + BN) * 64;
    constexpr int CA = BM / 32, CB = BN / 32;
    constexpr int LPT = CA + CB;
    static_assert(LPT >= 5 && LPT <= 8, "vmcnt literal range");
    __shared__ short lds[2 * TS];
    const int tid = threadIdx.x;
    const int lane = tid & 63, wid = tid >> 6;
    const int wm = wid >> 1, wn = wid & 1;
    const int bm = blockIdx.y * BM, bn = blockIdx.x * BN;
    const int li = lane & 15, gk = lane >> 4;

    f32x4 acc[FM][FN];
#pragma unroll
    for (int i = 0; i < FM; ++i)
#pragma unroll
        for (int j = 0; j < FN; ++j)
            acc[i][j] = f32x4{0.f, 0.f, 0.f, 0.f};

    auto stage = [&](int kt, int buf) {
        short* la = &lds[buf * TS];
        short* lb = la + BM * 64;
#pragma unroll
        for (int i = 0; i < CA; ++i) {
            int s = i * 256 + tid;
            int r = s >> 3, c = s & 7;
            gload16(A + (size_t)(bm + r) * K + kt * 64 + (c ^ (r & 7)) * 8,
                    (char*)la + (size_t)(i * 256 + wid * 64) * 16);
        }
#pragma unroll
        for (int i = 0; i < CB; ++i) {
            int s = i * 256 + tid;
            int r = s >> 3, c = s & 7;
            gload16(BT + (size_t)(bn + r) * K + kt * 64 + (c ^ (r & 7)) * 8,
                    (char*)lb + (size_t)(i * 256 + wid * 64) * 16);
        }
    };

    const int nkt = K >> 6;
    stage(0, 0);
    stage(1, 1);

    for (int t = 0; t < nkt; ++t) {
        if (t + 1 < nkt) {
            if constexpr (LPT == 5)      asm volatile("s_waitcnt vmcnt(5)" ::: "memory");
            else if constexpr (LPT == 6) asm volatile("s_waitcnt vmcnt(6)" ::: "memory");
            else if constexpr (LPT == 7) asm volatile("s_waitcnt vmcnt(7)" ::: "memory");
            else                         asm volatile("s_waitcnt vmcnt(8)" ::: "memory");
        } else {
            asm volatile("s_waitcnt vmcnt(0)" ::: "memory");
        }
        __builtin_amdgcn_s_barrier();

        const short* la = &lds[(t & 1) * TS];
        const short* lb = la + BM * 64;

        bf16x8 af0[FM], bf0[FN];
#pragma unroll
        for (int mi = 0; mi < FM; ++mi) {
            int row = (wm * FM + mi) * 16 + li;
            af0[mi] = *(const bf16x8*)&la[row * 64 + (gk ^ (row & 7)) * 8];
        }
#pragma unroll
        for (int ni = 0; ni < FN; ++ni) {
            int row = (wn * FN + ni) * 16 + li;
            bf0[ni] = *(const bf16x8*)&lb[row * 64 + (gk ^ (row & 7)) * 8];
        }
        __builtin_amdgcn_s_setprio(1);
#pragma unroll
        for (int mi = 0; mi < FM; ++mi)
#pragma unroll
            for (int ni = 0; ni < FN; ++ni)
                acc[mi][ni] = __builtin_amdgcn_mfma_f32_16x16x32_bf16(
                    af0[mi], bf0[ni], acc[mi][ni], 0, 0, 0);
        __builtin_amdgcn_s_setprio(0);

        bf16x8 af1[FM], bf1[FN];
#pragma unroll
        for (int mi = 0; mi < FM; ++mi) {
            int row = (wm * FM + mi) * 16 + li;
            af1[mi] = *(const bf16x8*)&la[row * 64 + ((4 + gk) ^ (row & 7)) * 8];
        }
#pragma unroll
        for (int ni = 0; ni < FN; ++ni) {
            int row = (wn * FN + ni) * 16 + li;
            bf1[ni] = *(const bf16x8*)&lb[row * 64 + ((4 + gk) ^ (row & 7)) * 8];
        }
        asm volatile("s_waitcnt lgkmcnt(0)" ::: "memory");
        __builtin_amdgcn_s_barrier();
        if (t + 2 < nkt) stage(t + 2, t & 1);
        __builtin_amdgcn_s_setprio(1);
#pragma unroll
        for (int mi = 0; mi < FM; ++mi)
#pragma unroll
            for (int ni = 0; ni < FN; ++ni)
                acc[mi][ni] = __builtin_amdgcn_mfma_f32_16x16x32_bf16(
                    af1[mi], bf1[ni], acc[mi][ni], 0, 0, 0);
        __builtin_amdgcn_s_setprio(0);
    }

#pragma unroll
    for (int mi = 0; mi < FM; ++mi) {
#pragma unroll
        for (int ni = 0; ni < FN; ++ni) {
            int col = bn + (wn * FN + ni) * 16 + li;
            float bv = bias[col];
            int row0 = bm + (wm * FM + mi) * 16 + gk * 4;
#pragma unroll
            for (int j = 0; j < 4; ++j) {
                int row = row0 + j;
                float v = acc[mi][ni][j] + bv;
                if (RELU) v = fmaxf(v, 0.0f);
                if (RESID) v += bs2f((unsigned short)resid[(size_t)row * N + col]);
                if (OUTBF16)
                    ((bf16*)Cout)[(size_t)row * N + col] = __float2bfloat16(v);
                else
                    ((float*)Cout)[(size_t)row * N + col] = v;
            }
        }
    }
}

// ---------------- MFMA flash attention, KVBLK=64, double-buffered K/V ----------------
__global__ __launch_bounds__(256) void attn_mfma(
    const short* __restrict__ qkv, const short* __restrict__ vT, bf16* __restrict__ y)
{
    const int qt = blockIdx.x, h = blockIdx.y, b = blockIdx.z;
    __shared__ short Ks[2][64 * 64];
    __shared__ short Vs[2][64 * 64];
    __shared__ short Ss[4][16][72];
    const int tid = threadIdx.x;
    const int lane = tid & 63, wid = tid >> 6;
    const int li = lane & 15, gk = lane >> 4;

    const size_t rowb = (size_t)b * cMB;
    int qr = qt * 64 + wid * 16 + li;
    int qrc = qr < cT ? qr : cT - 1;
    const short* qrow = qkv + (rowb + qrc) * cQKV + h * cHD;
    bf16x8 qf0 = *(const bf16x8*)(qrow + gk * 8);
    bf16x8 qf1 = *(const bf16x8*)(qrow + 32 + gk * 8);

    f32x4 o[4];
    float mrow[4], lrow[4];
#pragma unroll
    for (int dt = 0; dt < 4; ++dt) o[dt] = f32x4{0.f, 0.f, 0.f, 0.f};
#pragma unroll
    for (int j = 0; j < 4; ++j) { mrow[j] = -3e38f; lrow[j] = 0.f; }

    const int qloc = qt * 64 + wid * 16 + gk * 4;

    auto stage = [&](int kt, int buf) {
#pragma unroll
        for (int i = 0; i < 2; ++i) {
            int s = i * 256 + tid;
            int r = s >> 3, c = s & 7;
            gload16(qkv + (rowb + kt * 64 + r) * cQKV + cEX + h * cHD + (c ^ (r & 7)) * 8,
                    (char*)&Ks[buf][0] + (size_t)(i * 256 + wid * 64) * 16);
        }
#pragma unroll
        for (int i = 0; i < 2; ++i) {
            int s = i * 256 + tid;
            int d = s >> 3, c = s & 7;
            gload16(vT + (size_t)(h * cHD + d) * cMP + rowb + kt * 64 + (c ^ (d & 7)) * 8,
                    (char*)&Vs[buf][0] + (size_t)(i * 256 + wid * 64) * 16);
        }
    };

    const int nkt = qt + 1;
    stage(0, 0);
    for (int kt = 0; kt < nkt; ++kt) {
        if (kt + 1 < nkt) {
            stage(kt + 1, (kt + 1) & 1);
            asm volatile("s_waitcnt vmcnt(4)" ::: "memory");
        } else {
            asm volatile("s_waitcnt vmcnt(0)" ::: "memory");
        }
        __builtin_amdgcn_s_barrier();
        const int cur = kt & 1;

        f32x4 sg[4];
#pragma unroll
        for (int g = 0; g < 4; ++g) sg[g] = f32x4{0.f, 0.f, 0.f, 0.f};
#pragma unroll
        for (int g = 0; g < 4; ++g) {
            int key = g * 16 + li;
            bf16x8 k0 = *(const bf16x8*)&Ks[cur][key * 64 + (gk ^ (key & 7)) * 8];
            bf16x8 k1 = *(const bf16x8*)&Ks[cur][key * 64 + ((4 + gk) ^ (key & 7)) * 8];
            sg[g] = __builtin_amdgcn_mfma_f32_16x16x32_bf16(qf0, k0, sg[g], 0, 0, 0);
            sg[g] = __builtin_amdgcn_mfma_f32_16x16x32_bf16(qf1, k1, sg[g], 0, 0, 0);
        }

#pragma unroll
        for (int j = 0; j < 4; ++j) {
            int q = qloc + j;
            float sc[4];
#pragma unroll
            for (int g = 0; g < 4; ++g) {
                int kg = kt * 64 + g * 16 + li;
                sc[g] = (kg <= q) ? sg[g][j] * 0.125f : -3e38f;
            }
            float tm = fmaxf(fmaxf(sc[0], sc[1]), fmaxf(sc[2], sc[3]));
            tm = fmaxf(tm, __shfl_xor(tm, 1, 16));
            tm = fmaxf(tm, __shfl_xor(tm, 2, 16));
            tm = fmaxf(tm, __shfl_xor(tm, 4, 16));
            tm = fmaxf(tm, __shfl_xor(tm, 8, 16));
            float mnew = fmaxf(mrow[j], tm);
            float p[4], ps = 0.f;
#pragma unroll
            for (int g = 0; g < 4; ++g) { p[g] = __expf(sc[g] - mnew); ps += p[g]; }
            ps += __shfl_xor(ps, 1, 16);
            ps += __shfl_xor(ps, 2, 16);
            ps += __shfl_xor(ps, 4, 16);
            ps += __shfl_xor(ps, 8, 16);
            float scale = __expf(mrow[j] - mnew);
            lrow[j] = lrow[j] * scale + ps;
            mrow[j] = mnew;
#pragma unroll
            for (int dt = 0; dt < 4; ++dt) o[dt][j] *= scale;
#pragma unroll
            for (int g = 0; g < 4; ++g)
                Ss[wid][gk * 4 + j][g * 16 + li] = f2bs(p[g]);
        }

        bf16x8 pa0 = *(const bf16x8*)&Ss[wid][li][gk * 8];
        bf16x8 pa1 = *(const bf16x8*)&Ss[wid][li][32 + gk * 8];
#pragma unroll
        for (int dt = 0; dt < 4; ++dt) {
            int d = dt * 16 + li;
            bf16x8 vf0 = *(const bf16x8*)&Vs[cur][d * 64 + (gk ^ (d & 7)) * 8];
            bf16x8 vf1 = *(const bf16x8*)&Vs[cur][d * 64 + ((4 + gk) ^ (d & 7)) * 8];
            o[dt] = __builtin_amdgcn_mfma_f32_16x16x32_bf16(pa0, vf0, o[dt], 0, 0, 0);
            o[dt] = __builtin_amdgcn_mfma_f32_16x16x32_bf16(pa1, vf1, o[dt], 0, 0, 0);
        }
        asm volatile("s_waitcnt lgkmcnt(0)" ::: "memory");
        __builtin_amdgcn_s_barrier();
    }

#pragma unroll
    for (int j = 0; j < 4; ++j) {
        int q = qloc + j;
        if (q >= cT) continue;
        float inv = 1.0f / lrow[j];
        bf16* yr = y + (rowb + q) * cEX + h * cHD;
#pragma unroll
        for (int dt = 0; dt < 4; ++dt)
            yr[dt * 16 + li] = __float2bfloat16(o[dt][j] * inv);
    }
}

// ---------------- head with fused final LN (x is bf16) ----------------
__global__ __launch_bounds__(256) void head_part_kernel(
    const short* __restrict__ x, const float* __restrict__ lnf_s,
    const float* __restrict__ lnf_b, const float* __restrict__ hw,
    float* __restrict__ part)
{
    __shared__ float xs[8][1536];
    __shared__ float stat[16][2];
    const int tid = threadIdx.x;
    const int trow0 = blockIdx.x * 2;
    const int wid = tid >> 6, lane = tid & 63;
    {
        const int g = lane >> 4, li = lane & 15;
        const int p = wid * 4 + g, bb = p >> 1, rr = p & 1;
        const short* xr = x + ((size_t)(bb * cMB + trow0 + rr)) * cEX;
        float sum = 0.f, sq = 0.f;
#pragma unroll
        for (int it = 0; it < 12; ++it) {
            ushort4 raw = *(const ushort4*)&xr[it * 64 + li * 4];
            float a0 = bs2f(raw.x), a1 = bs2f(raw.y), a2 = bs2f(raw.z), a3 = bs2f(raw.w);
            sum += a0 + a1 + a2 + a3;
            sq  += a0 * a0 + a1 * a1 + a2 * a2 + a3 * a3;
        }
#pragma unroll
        for (int off = 8; off > 0; off >>= 1) {
            sum += __shfl_xor(sum, off, 16);
            sq  += __shfl_xor(sq, off, 16);
        }
        if (li == 0) {
            float mean = sum * (1.0f / cEX);
            float var = sq * (1.0f / cEX) - mean * mean;
            stat[p][0] = mean;
            stat[p][1] = rsqrtf(var + 1e-5f);
        }
    }
    __syncthreads();
    for (int i = tid; i < 8 * 1536; i += 256) {
        int bb = i / 1536, kk = i - bb * 1536;
        int rr = kk >= cEX ? 1 : 0;
        int e = kk - rr * cEX;
        float mean = stat[bb * 2 + rr][0], rstd = stat[bb * 2 + rr][1];
        float val = bs2f((unsigned short)x[((size_t)(bb * cMB + trow0 + rr)) * cEX + e]);
        xs[bb][kk] = (val - mean) * rstd * lnf_s[e] + lnf_b[e];
    }
    __syncthreads();
    float acc[8] = {};
    const int k0 = blockIdx.x * 1536;
    const float* wp = hw + (size_t)k0 * cVOC + tid;
    for (int kk = 0; kk < 1536; ++kk) {
        float w = wp[(size_t)kk * cVOC];
#pragma unroll
        for (int bb = 0; bb < 8; ++bb) acc[bb] += xs[bb][kk] * w;
    }
#pragma unroll
    for (int bb = 0; bb < 8; ++bb)
        part[((size_t)blockIdx.x * 8 + bb) * cVOC + tid] = acc[bb];
}

__global__ __launch_bounds__(256) void head_reduce_kernel(
    const float* __restrict__ part, const float* __restrict__ hb, float* __restrict__ out)
{
    int i = blockIdx.x * 256 + threadIdx.x;
    int bb = i >> 8, vv = i & 255;
    float acc = hb[vv];
    for (int c = 0; c < 255; ++c) acc += part[((size_t)c * 8 + bb) * 256 + vv];
    out[i] = acc;
}

// ---------------- launch ----------------
extern "C" void kernel_launch(void* const* d_in, const int* in_sizes, int n_in,
                              void* d_out, int out_size, void* d_ws, size_t ws_size,
                              hipStream_t stream) {
    (void)in_sizes; (void)n_in; (void)out_size; (void)ws_size;
    const int*   idx    = (const int*)d_in[0];
    const float* lin_w  = (const float*)d_in[1];
    const float* lin_b  = (const float*)d_in[2];
    const float* ln1_s  = (const float*)d_in[3];
    const float* ln1_b  = (const float*)d_in[4];
    const float* qw     = (const float*)d_in[5];
    const float* qbias  = (const float*)d_in[6];
    const float* kw     = (const float*)d_in[7];
    const float* kbias  = (const float*)d_in[8];
    const float* vw     = (const float*)d_in[9];
    const float* vbias  = (const float*)d_in[10];
    const float* ew     = (const float*)d_in[11];
    const float* ebias  = (const float*)d_in[12];
    const float* ln2_s  = (const float*)d_in[13];
    const float* ln2_b  = (const float*)d_in[14];
    const float* m1w    = (const float*)d_in[15];
    const float* m1b    = (const float*)d_in[16];
    const float* m2w    = (const float*)d_in[17];
    const float* m2b    = (const float*)d_in[18];
    const float* lnf_s  = (const float*)d_in[19];
    const float* lnf_b  = (const float*)d_in[20];
    const float* head_w = (const float*)d_in[21];
    const float* head_b = (const float*)d_in[22];
    float* out = (float*)d_out;

    const size_t act = (size_t)cMP * cEX;
    float* part = (float*)d_ws;                    // 255*8*256
    float* qkvb = part + 255 * 8 * 256;            // [11][2304]
    short* x    = (short*)(qkvb + cNBLK * cQKV);   // [4096][768] bf16 residual
    short* qkv  = x + act;                         // [4096][2304] bf16 (V region unused)
    short* vTr  = qkv + (size_t)cMP * cQKV;        // [768][4096] bf16
    short* h    = vTr + (size_t)cEX * cMP;         // [4096][768] bf16
    short* h2   = h + act;
    short* y    = h2 + act;
    short* u    = y + act;                         // [4096][3072] bf16
    short* wqkvT = u + (size_t)cMP * 4 * cEX;      // [11][2304][768]
    short* weT   = wqkvT + (size_t)cNBLK * cQKV * cEX;
    short* wm1T  = weT + (size_t)cNBLK * cEX * cEX;
    short* wm2T  = wm1T + (size_t)cNBLK * cEX * 4 * cEX;

    transpose_qkv<<<dim3(24, 24, 3 * cNBLK), 256, 0, stream>>>(qw, kw, vw, (bf16*)wqkvT);
    transpose_w<<<dim3(24, 24, cNBLK), 256, 0, stream>>>(ew, (bf16*)weT, cEX, cEX,
        (size_t)cEX * cEX, (size_t)cEX * cEX, 0);
    transpose_w<<<dim3(96, 24, cNBLK), 256, 0, stream>>>(m1w, (bf16*)wm1T, cEX, 4 * cEX,
        (size_t)cEX * 4 * cEX, (size_t)cEX * 4 * cEX, 0);
    transpose_w<<<dim3(24, 96, cNBLK), 256, 0, stream>>>(m2w, (bf16*)wm2T, 4 * cEX, cEX,
        (size_t)cEX * 4 * cEX, (size_t)cEX * 4 * cEX, 0);
    concat_bias<<<(cNBLK * cQKV + 255) / 256, 256, 0, stream>>>(qbias, kbias, vbias, qkvb);

    embed_kernel<<<cMP, 256, 0, stream>>>(idx, lin_w, lin_b, x);

    for (int blk = 0; blk < cNBLK; ++blk) {
        size_t bo = (size_t)blk * cEX;
        ln_wave<<<cMP / 4, 256, 0, stream>>>(x, ln1_s + bo, ln1_b + bo, h);
        // QKV fused: 128x128 tile, 32x32 MFMA; V columns written transposed into vTr
        gemm32<false, true><<<dim3(cQKV / 128, cMP / 128), 256, 0, stream>>>(
            h, wqkvT + (size_t)blk * cQKV * cEX, qkvb + (size_t)blk * cQKV,
            qkv, vTr, cEX, cQKV);
        attn_mfma<<<dim3(8, cNH, cB), 256, 0, stream>>>(qkv, vTr, (bf16*)y);
        // eproj: 64x96 tile (16x16 MFMA) -> grid 8x64 = 512 blocks (2/CU exact)
        gemm_db<2, 3, false, true, true><<<dim3(cEX / 96, cMP / 64), 256, 0, stream>>>(
            y, weT + (size_t)blk * cEX * cEX, ebias + bo, x, x, cEX, cEX);
        ln_wave<<<cMP / 4, 256, 0, stream>>>(x, ln2_s + bo, ln2_b + bo, h2);
        // m1: 128x128 tile, 32x32 MFMA -> 24x32 = 768 blocks (3/CU exact)
        gemm32<true, false><<<dim3(4 * cEX / 128, cMP / 128), 256, 0, stream>>>(
            h2, wm1T + (size_t)blk * cEX * 4 * cEX, m1b + (size_t)blk * 4 * cEX,
            u, nullptr, cEX, 4 * cEX);
        // m2: 64x96 -> 8x64 = 512 blocks (2/CU exact)
        gemm_db<2, 3, false, true, true><<<dim3(cEX / 96, cMP / 64), 256, 0, stream>>>(
            u, wm2T + (size_t)blk * cEX * 4 * cEX, m2b + bo, x, x, 4 * cEX, cEX);
    }
    head_part_kernel<<<255, 256, 0, stream>>>(x, lnf_s, lnf_b, head_w, part);
    head_reduce_kernel<<<8, 256, 0, stream>>>(part, head_b, out);
}

// Round 13
// 1670.709 us; speedup vs baseline: 1.0781x; 1.0781x over previous
//
#include <hip/hip_runtime.h>
#include <hip/hip_bf16.h>
#include <math.h>

constexpr int cB = 8, cT = 510, cNH = 12, cEX = 768, cVOC = 256, cNBLK = 11, cHD = 64;
constexpr int cMB = 512;         // padded rows per batch
constexpr int cMP = 4096;        // total padded rows (8*512)
constexpr int cQKV = 3 * cEX;    // 2304

typedef __attribute__((ext_vector_type(8))) short bf16x8;
typedef __attribute__((ext_vector_type(4))) float f32x4;
using bf16 = __hip_bfloat16;

__device__ inline void gload16(const void* g, void* l) {
    __builtin_amdgcn_global_load_lds((const __attribute__((address_space(1))) unsigned int*)g,
                                     (__attribute__((address_space(3))) unsigned int*)l, 16, 0, 0);
}
__device__ inline short f2bs(float f) {
    bf16 b = __float2bfloat16(f);
    return *reinterpret_cast<short*>(&b);
}
__device__ inline float bs2f(unsigned short s) {
    unsigned int u = ((unsigned int)s) << 16;
    float f;
    __builtin_memcpy(&f, &u, 4);
    return f;
}

// ---------------- embedding: rows b*512+t, zero pads; x is bf16 ----------------
__global__ __launch_bounds__(256) void embed_kernel(
    const int* __restrict__ idx, const float* __restrict__ lin_w,
    const float* __restrict__ lin_b, short* __restrict__ x)
{
    int row = blockIdx.x;
    int b = row >> 9, t = row & 511;
    short* xr = x + (size_t)row * cEX;
    if (t >= cT) {
        for (int j = threadIdx.x; j < cEX; j += 256) xr[j] = 0;
        return;
    }
    int tok = idx[b * cT + t] & 1;
    const float* wt = lin_w + (size_t)tok * cEX;
    const float* wp = lin_w + (size_t)(2 + t) * cEX;
    for (int j = threadIdx.x; j < cEX; j += 256) {
        float val = wt[j] + wp[j] + lin_b[j];
        xr[j] = f2bs(fmaxf(val, 0.0f));
    }
}

// ---------------- layernorm: one row per wave, bf16 in -> bf16 out ----------------
__global__ __launch_bounds__(256) void ln_wave(
    const short* __restrict__ in, const float* __restrict__ s,
    const float* __restrict__ bsh, short* __restrict__ out)
{
    const int wid = threadIdx.x >> 6, lane = threadIdx.x & 63;
    const int row = blockIdx.x * 4 + wid;
    const short* xr = in + (size_t)row * cEX;
    float v[12];
    float sum = 0.f, sq = 0.f;
#pragma unroll
    for (int p = 0; p < 3; ++p) {
        ushort4 raw = *(const ushort4*)&xr[p * 256 + lane * 4];
        v[p * 4 + 0] = bs2f(raw.x); v[p * 4 + 1] = bs2f(raw.y);
        v[p * 4 + 2] = bs2f(raw.z); v[p * 4 + 3] = bs2f(raw.w);
#pragma unroll
        for (int q = 0; q < 4; ++q) { sum += v[p * 4 + q]; sq += v[p * 4 + q] * v[p * 4 + q]; }
    }
#pragma unroll
    for (int off = 1; off < 64; off <<= 1) {
        sum += __shfl_xor(sum, off, 64);
        sq  += __shfl_xor(sq, off, 64);
    }
    float mean = sum * (1.0f / cEX);
    float var = sq * (1.0f / cEX) - mean * mean;
    float rstd = rsqrtf(var + 1e-5f);
    short* outr = out + (size_t)row * cEX;
#pragma unroll
    for (int p = 0; p < 3; ++p) {
        int c = p * 256 + lane * 4;
        float4 sv = *(const float4*)&s[c];
        float4 bv = *(const float4*)&bsh[c];
        short4 pk;
        pk.x = f2bs((v[p * 4 + 0] - mean) * rstd * sv.x + bv.x);
        pk.y = f2bs((v[p * 4 + 1] - mean) * rstd * sv.y + bv.y);
        pk.z = f2bs((v[p * 4 + 2] - mean) * rstd * sv.z + bv.z);
        pk.w = f2bs((v[p * 4 + 3] - mean) * rstd * sv.w + bv.w);
        *(short4*)&outr[c] = pk;
    }
}

// ---------------- weight transpose + fp32->bf16: W[K][N] -> WT[N][K] ----------------
__global__ __launch_bounds__(256) void transpose_w(
    const float* __restrict__ W, bf16* __restrict__ WT,
    int K, int N, size_t w_stride, size_t wt_stride, int wt_row_off)
{
    __shared__ float t[32][33];
    const float* Wb = W + (size_t)blockIdx.z * w_stride;
    bf16* WTb = WT + (size_t)blockIdx.z * wt_stride;
    int n0 = blockIdx.x * 32, k0 = blockIdx.y * 32;
    int c = threadIdx.x & 31, ty = threadIdx.x >> 5;
#pragma unroll
    for (int it = 0; it < 4; ++it) {
        int r = ty + it * 8;
        t[r][c] = Wb[(size_t)(k0 + r) * N + n0 + c];
    }
    __syncthreads();
#pragma unroll
    for (int it = 0; it < 4; ++it) {
        int a = ty + it * 8;
        WTb[(size_t)(wt_row_off + n0 + a) * K + k0 + c] = __float2bfloat16(t[c][a]);
    }
}

// ---------------- fused q/k/v weight transpose: z = blk*3 + which ----------------
__global__ __launch_bounds__(256) void transpose_qkv(
    const float* __restrict__ qw, const float* __restrict__ kw,
    const float* __restrict__ vw, bf16* __restrict__ WT)
{
    __shared__ float t[32][33];
    int z = blockIdx.z;
    int blk = z / 3, which = z - blk * 3;
    const float* Wb = (which == 0 ? qw : which == 1 ? kw : vw) + (size_t)blk * cEX * cEX;
    bf16* WTb = WT + (size_t)blk * cQKV * cEX + (size_t)which * cEX * cEX;
    int n0 = blockIdx.x * 32, k0 = blockIdx.y * 32;
    int c = threadIdx.x & 31, ty = threadIdx.x >> 5;
#pragma unroll
    for (int it = 0; it < 4; ++it) {
        int r = ty + it * 8;
        t[r][c] = Wb[(size_t)(k0 + r) * cEX + n0 + c];
    }
    __syncthreads();
#pragma unroll
    for (int it = 0; it < 4; ++it) {
        int a = ty + it * 8;
        WTb[(size_t)(n0 + a) * cEX + k0 + c] = __float2bfloat16(t[c][a]);
    }
}

// ---------------- concat q/k/v biases ----------------
__global__ __launch_bounds__(256) void concat_bias(
    const float* __restrict__ qb, const float* __restrict__ kb,
    const float* __restrict__ vb, float* __restrict__ qkvb)
{
    int i = blockIdx.x * 256 + threadIdx.x;
    if (i >= cNBLK * cQKV) return;
    int blk = i / cQKV, c = i - blk * cQKV;
    const float* src; int cc = c;
    if (c < cEX)            { src = qb; }
    else if (c < 2 * cEX)   { src = kb; cc = c - cEX; }
    else                    { src = vb; cc = c - 2 * cEX; }
    qkvb[i] = src[(size_t)blk * cEX + cc];
}

// ---------------- MFMA GEMM: 2x2 waves, BK=64, dbuf, counted vmcnt, ks split ----------------
// Proven r11 config: vmcnt(LPT)+barrier publishes tile t (all waves' loads),
// lgkmcnt(0)+barrier certifies reads done before re-staging, stage 2-ahead.
template<int FM, int FN, bool RELU, bool RESID, bool OUTBF16, bool VT>
__global__ __launch_bounds__(256) void gemm_db(
    const short* __restrict__ A, const short* __restrict__ BT,
    const float* __restrict__ bias, const short* __restrict__ resid,
    void* __restrict__ Cout, short* __restrict__ vTr, int K, int N)
{
    constexpr int BM = FM * 32, BN = FN * 32;
    constexpr int TS = (BM + BN) * 64;          // shorts per K-tile buffer
    constexpr int CA = BM / 32, CB = BN / 32;   // gload16 per thread for A / B
    constexpr int LPT = CA + CB;
    static_assert(LPT >= 5 && LPT <= 8, "vmcnt literal range");
    __shared__ short lds[2 * TS];
    const int tid = threadIdx.x;
    const int lane = tid & 63, wid = tid >> 6;
    const int wm = wid >> 1, wn = wid & 1;
    const int bm = blockIdx.y * BM, bn = blockIdx.x * BN;
    const int li = lane & 15, gk = lane >> 4;

    f32x4 acc[FM][FN];
#pragma unroll
    for (int i = 0; i < FM; ++i)
#pragma unroll
        for (int j = 0; j < FN; ++j)
            acc[i][j] = f32x4{0.f, 0.f, 0.f, 0.f};

    auto stage = [&](int kt, int buf) {
        short* la = &lds[buf * TS];
        short* lb = la + BM * 64;
#pragma unroll
        for (int i = 0; i < CA; ++i) {
            int s = i * 256 + tid;
            int r = s >> 3, c = s & 7;
            gload16(A + (size_t)(bm + r) * K + kt * 64 + (c ^ (r & 7)) * 8,
                    (char*)la + (size_t)(i * 256 + wid * 64) * 16);
        }
#pragma unroll
        for (int i = 0; i < CB; ++i) {
            int s = i * 256 + tid;
            int r = s >> 3, c = s & 7;
            gload16(BT + (size_t)(bn + r) * K + kt * 64 + (c ^ (r & 7)) * 8,
                    (char*)lb + (size_t)(i * 256 + wid * 64) * 16);
        }
    };

    const int nkt = K >> 6;
    stage(0, 0);
    stage(1, 1);

    for (int t = 0; t < nkt; ++t) {
        if (t + 1 < nkt) {
            if constexpr (LPT == 5)      asm volatile("s_waitcnt vmcnt(5)" ::: "memory");
            else if constexpr (LPT == 6) asm volatile("s_waitcnt vmcnt(6)" ::: "memory");
            else if constexpr (LPT == 7) asm volatile("s_waitcnt vmcnt(7)" ::: "memory");
            else                         asm volatile("s_waitcnt vmcnt(8)" ::: "memory");
        } else {
            asm volatile("s_waitcnt vmcnt(0)" ::: "memory");
        }
        __builtin_amdgcn_s_barrier();

        const short* la = &lds[(t & 1) * TS];
        const short* lb = la + BM * 64;

        // ---- phase 1: ks0 ----
        bf16x8 af0[FM], bf0[FN];
#pragma unroll
        for (int mi = 0; mi < FM; ++mi) {
            int row = (wm * FM + mi) * 16 + li;
            af0[mi] = *(const bf16x8*)&la[row * 64 + (gk ^ (row & 7)) * 8];
        }
#pragma unroll
        for (int ni = 0; ni < FN; ++ni) {
            int row = (wn * FN + ni) * 16 + li;
            bf0[ni] = *(const bf16x8*)&lb[row * 64 + (gk ^ (row & 7)) * 8];
        }
        __builtin_amdgcn_s_setprio(1);
#pragma unroll
        for (int mi = 0; mi < FM; ++mi)
#pragma unroll
            for (int ni = 0; ni < FN; ++ni)
                acc[mi][ni] = __builtin_amdgcn_mfma_f32_16x16x32_bf16(
                    af0[mi], bf0[ni], acc[mi][ni], 0, 0, 0);
        __builtin_amdgcn_s_setprio(0);

        // ---- phase 2: ks1 reads, free buffer, stage, compute ----
        bf16x8 af1[FM], bf1[FN];
#pragma unroll
        for (int mi = 0; mi < FM; ++mi) {
            int row = (wm * FM + mi) * 16 + li;
            af1[mi] = *(const bf16x8*)&la[row * 64 + ((4 + gk) ^ (row & 7)) * 8];
        }
#pragma unroll
        for (int ni = 0; ni < FN; ++ni) {
            int row = (wn * FN + ni) * 16 + li;
            bf1[ni] = *(const bf16x8*)&lb[row * 64 + ((4 + gk) ^ (row & 7)) * 8];
        }
        asm volatile("s_waitcnt lgkmcnt(0)" ::: "memory");
        __builtin_amdgcn_s_barrier();
        if (t + 2 < nkt) stage(t + 2, t & 1);
        __builtin_amdgcn_s_setprio(1);
#pragma unroll
        for (int mi = 0; mi < FM; ++mi)
#pragma unroll
            for (int ni = 0; ni < FN; ++ni)
                acc[mi][ni] = __builtin_amdgcn_mfma_f32_16x16x32_bf16(
                    af1[mi], bf1[ni], acc[mi][ni], 0, 0, 0);
        __builtin_amdgcn_s_setprio(0);
    }

    // epilogue: C/D layout col=lane&15, row=(lane>>4)*4+j
#pragma unroll
    for (int mi = 0; mi < FM; ++mi) {
#pragma unroll
        for (int ni = 0; ni < FN; ++ni) {
            int col = bn + (wn * FN + ni) * 16 + li;
            float bv = bias[col];
            int row0 = bm + (wm * FM + mi) * 16 + gk * 4;
            if (VT && col >= 2 * cEX) {
                short4 pk;
                pk.x = f2bs(acc[mi][ni][0] + bv);
                pk.y = f2bs(acc[mi][ni][1] + bv);
                pk.z = f2bs(acc[mi][ni][2] + bv);
                pk.w = f2bs(acc[mi][ni][3] + bv);
                *(short4*)&vTr[(size_t)(col - 2 * cEX) * cMP + row0] = pk;
            } else {
#pragma unroll
                for (int j = 0; j < 4; ++j) {
                    int row = row0 + j;
                    float v = acc[mi][ni][j] + bv;
                    if (RELU) v = fmaxf(v, 0.0f);
                    if (RESID) v += bs2f((unsigned short)resid[(size_t)row * N + col]);
                    if (OUTBF16)
                        ((bf16*)Cout)[(size_t)row * N + col] = __float2bfloat16(v);
                    else
                        ((float*)Cout)[(size_t)row * N + col] = v;
                }
            }
        }
    }
}

// ---------------- MFMA flash attention, KVBLK=64, dbuf K/V, qt-balanced 1D grid ----------------
// bid in [0,768): j=bid>>3 -> (h,b); qt = {q8, 7-q8, (q8+j)&7} per 256-range.
// Bijective: within fixed j, each range's qt(q8) is a bijection on [0,8).
// Balances per-CU work (blocks i,i+256,i+512 share i%8 -> same qt without remap).
__global__ __launch_bounds__(256) void attn_mfma(
    const short* __restrict__ qkv, const short* __restrict__ vT, bf16* __restrict__ y)
{
    const int bid = blockIdx.x;
    const int q8 = bid & 7;
    const int j = bid >> 3;            // 0..95
    const int rng = bid >> 8;          // 0,1,2
    int qt;
    if (rng == 0)      qt = q8;
    else if (rng == 1) qt = 7 - q8;
    else               qt = (q8 + j) & 7;
    const int h = j % cNH, b = j / cNH;

    __shared__ short Ks[2][64 * 64];   // [key][d], chunk-swizzled
    __shared__ short Vs[2][64 * 64];   // [d][key], chunk-swizzled
    __shared__ short Ss[4][16][72];    // per-wave P (bf16)
    const int tid = threadIdx.x;
    const int lane = tid & 63, wid = tid >> 6;
    const int li = lane & 15, gk = lane >> 4;

    const size_t rowb = (size_t)b * cMB;
    int qr = qt * 64 + wid * 16 + li;
    int qrc = qr < cT ? qr : cT - 1;
    const short* qrow = qkv + (rowb + qrc) * cQKV + h * cHD;
    bf16x8 qf0 = *(const bf16x8*)(qrow + gk * 8);
    bf16x8 qf1 = *(const bf16x8*)(qrow + 32 + gk * 8);

    f32x4 o[4];
    float mrow[4], lrow[4];
#pragma unroll
    for (int dt = 0; dt < 4; ++dt) o[dt] = f32x4{0.f, 0.f, 0.f, 0.f};
#pragma unroll
    for (int jj = 0; jj < 4; ++jj) { mrow[jj] = -3e38f; lrow[jj] = 0.f; }

    const int qloc = qt * 64 + wid * 16 + gk * 4;

    auto stage = [&](int kt, int buf) {
#pragma unroll
        for (int i = 0; i < 2; ++i) {
            int s = i * 256 + tid;
            int r = s >> 3, c = s & 7;
            gload16(qkv + (rowb + kt * 64 + r) * cQKV + cEX + h * cHD + (c ^ (r & 7)) * 8,
                    (char*)&Ks[buf][0] + (size_t)(i * 256 + wid * 64) * 16);
        }
#pragma unroll
        for (int i = 0; i < 2; ++i) {
            int s = i * 256 + tid;
            int d = s >> 3, c = s & 7;
            gload16(vT + (size_t)(h * cHD + d) * cMP + rowb + kt * 64 + (c ^ (d & 7)) * 8,
                    (char*)&Vs[buf][0] + (size_t)(i * 256 + wid * 64) * 16);
        }
    };

    const int nkt = qt + 1;
    stage(0, 0);
    for (int kt = 0; kt < nkt; ++kt) {
        if (kt + 1 < nkt) {
            stage(kt + 1, (kt + 1) & 1);
            asm volatile("s_waitcnt vmcnt(4)" ::: "memory");
        } else {
            asm volatile("s_waitcnt vmcnt(0)" ::: "memory");
        }
        __builtin_amdgcn_s_barrier();
        const int cur = kt & 1;

        // QK^T: 4 key-subtiles of 16, 2 d-halves each
        f32x4 sg[4];
#pragma unroll
        for (int g = 0; g < 4; ++g) sg[g] = f32x4{0.f, 0.f, 0.f, 0.f};
        __builtin_amdgcn_s_setprio(1);
#pragma unroll
        for (int g = 0; g < 4; ++g) {
            int key = g * 16 + li;
            bf16x8 k0 = *(const bf16x8*)&Ks[cur][key * 64 + (gk ^ (key & 7)) * 8];
            bf16x8 k1 = *(const bf16x8*)&Ks[cur][key * 64 + ((4 + gk) ^ (key & 7)) * 8];
            sg[g] = __builtin_amdgcn_mfma_f32_16x16x32_bf16(qf0, k0, sg[g], 0, 0, 0);
            sg[g] = __builtin_amdgcn_mfma_f32_16x16x32_bf16(qf1, k1, sg[g], 0, 0, 0);
        }
        __builtin_amdgcn_s_setprio(0);

        // mask + scale + online softmax (row jj, reduce over 16 lanes li)
#pragma unroll
        for (int jj = 0; jj < 4; ++jj) {
            int q = qloc + jj;
            float sc[4];
#pragma unroll
            for (int g = 0; g < 4; ++g) {
                int kg = kt * 64 + g * 16 + li;
                sc[g] = (kg <= q) ? sg[g][jj] * 0.125f : -3e38f;
            }
            float tm = fmaxf(fmaxf(sc[0], sc[1]), fmaxf(sc[2], sc[3]));
            tm = fmaxf(tm, __shfl_xor(tm, 1, 16));
            tm = fmaxf(tm, __shfl_xor(tm, 2, 16));
            tm = fmaxf(tm, __shfl_xor(tm, 4, 16));
            tm = fmaxf(tm, __shfl_xor(tm, 8, 16));
            float mnew = fmaxf(mrow[jj], tm);
            float p[4], ps = 0.f;
#pragma unroll
            for (int g = 0; g < 4; ++g) { p[g] = __expf(sc[g] - mnew); ps += p[g]; }
            ps += __shfl_xor(ps, 1, 16);
            ps += __shfl_xor(ps, 2, 16);
            ps += __shfl_xor(ps, 4, 16);
            ps += __shfl_xor(ps, 8, 16);
            float scale = __expf(mrow[jj] - mnew);
            lrow[jj] = lrow[jj] * scale + ps;
            mrow[jj] = mnew;
#pragma unroll
            for (int dt = 0; dt < 4; ++dt) o[dt][jj] *= scale;
#pragma unroll
            for (int g = 0; g < 4; ++g)
                Ss[wid][gk * 4 + jj][g * 16 + li] = f2bs(p[g]);
        }

        // PV: two 32-key halves
        bf16x8 pa0 = *(const bf16x8*)&Ss[wid][li][gk * 8];
        bf16x8 pa1 = *(const bf16x8*)&Ss[wid][li][32 + gk * 8];
        __builtin_amdgcn_s_setprio(1);
#pragma unroll
        for (int dt = 0; dt < 4; ++dt) {
            int d = dt * 16 + li;
            bf16x8 vf0 = *(const bf16x8*)&Vs[cur][d * 64 + (gk ^ (d & 7)) * 8];
            bf16x8 vf1 = *(const bf16x8*)&Vs[cur][d * 64 + ((4 + gk) ^ (d & 7)) * 8];
            o[dt] = __builtin_amdgcn_mfma_f32_16x16x32_bf16(pa0, vf0, o[dt], 0, 0, 0);
            o[dt] = __builtin_amdgcn_mfma_f32_16x16x32_bf16(pa1, vf1, o[dt], 0, 0, 0);
        }
        __builtin_amdgcn_s_setprio(0);
        asm volatile("s_waitcnt lgkmcnt(0)" ::: "memory");
        __builtin_amdgcn_s_barrier();
    }

#pragma unroll
    for (int jj = 0; jj < 4; ++jj) {
        int q = qloc + jj;
        if (q >= cT) continue;
        float inv = 1.0f / lrow[jj];
        bf16* yr = y + (rowb + q) * cEX + h * cHD;
#pragma unroll
        for (int dt = 0; dt < 4; ++dt)
            yr[dt * 16 + li] = __float2bfloat16(o[dt][jj] * inv);
    }
}

// ---------------- head with fused final LN (x is bf16) ----------------
__global__ __launch_bounds__(256) void head_part_kernel(
    const short* __restrict__ x, const float* __restrict__ lnf_s,
    const float* __restrict__ lnf_b, const float* __restrict__ hw,
    float* __restrict__ part)
{
    __shared__ float xs[8][1536];
    __shared__ float stat[16][2];
    const int tid = threadIdx.x;
    const int trow0 = blockIdx.x * 2;
    const int wid = tid >> 6, lane = tid & 63;
    {
        const int g = lane >> 4, li = lane & 15;
        const int p = wid * 4 + g, bb = p >> 1, rr = p & 1;
        const short* xr = x + ((size_t)(bb * cMB + trow0 + rr)) * cEX;
        float sum = 0.f, sq = 0.f;
#pragma unroll
        for (int it = 0; it < 12; ++it) {
            ushort4 raw = *(const ushort4*)&xr[it * 64 + li * 4];
            float a0 = bs2f(raw.x), a1 = bs2f(raw.y), a2 = bs2f(raw.z), a3 = bs2f(raw.w);
            sum += a0 + a1 + a2 + a3;
            sq  += a0 * a0 + a1 * a1 + a2 * a2 + a3 * a3;
        }
#pragma unroll
        for (int off = 8; off > 0; off >>= 1) {
            sum += __shfl_xor(sum, off, 16);
            sq  += __shfl_xor(sq, off, 16);
        }
        if (li == 0) {
            float mean = sum * (1.0f / cEX);
            float var = sq * (1.0f / cEX) - mean * mean;
            stat[p][0] = mean;
            stat[p][1] = rsqrtf(var + 1e-5f);
        }
    }
    __syncthreads();
    for (int i = tid; i < 8 * 1536; i += 256) {
        int bb = i / 1536, kk = i - bb * 1536;
        int rr = kk >= cEX ? 1 : 0;
        int e = kk - rr * cEX;
        float mean = stat[bb * 2 + rr][0], rstd = stat[bb * 2 + rr][1];
        float val = bs2f((unsigned short)x[((size_t)(bb * cMB + trow0 + rr)) * cEX + e]);
        xs[bb][kk] = (val - mean) * rstd * lnf_s[e] + lnf_b[e];
    }
    __syncthreads();
    float acc[8] = {};
    const int k0 = blockIdx.x * 1536;
    const float* wp = hw + (size_t)k0 * cVOC + tid;
    for (int kk = 0; kk < 1536; ++kk) {
        float w = wp[(size_t)kk * cVOC];
#pragma unroll
        for (int bb = 0; bb < 8; ++bb) acc[bb] += xs[bb][kk] * w;
    }
#pragma unroll
    for (int bb = 0; bb < 8; ++bb)
        part[((size_t)blockIdx.x * 8 + bb) * cVOC + tid] = acc[bb];
}

__global__ __launch_bounds__(256) void head_reduce_kernel(
    const float* __restrict__ part, const float* __restrict__ hb, float* __restrict__ out)
{
    int i = blockIdx.x * 256 + threadIdx.x;
    int bb = i >> 8, vv = i & 255;
    float acc = hb[vv];
    for (int c = 0; c < 255; ++c) acc += part[((size_t)c * 8 + bb) * 256 + vv];
    out[i] = acc;
}

// ---------------- launch ----------------
extern "C" void kernel_launch(void* const* d_in, const int* in_sizes, int n_in,
                              void* d_out, int out_size, void* d_ws, size_t ws_size,
                              hipStream_t stream) {
    (void)in_sizes; (void)n_in; (void)out_size; (void)ws_size;
    const int*   idx    = (const int*)d_in[0];
    const float* lin_w  = (const float*)d_in[1];
    const float* lin_b  = (const float*)d_in[2];
    const float* ln1_s  = (const float*)d_in[3];
    const float* ln1_b  = (const float*)d_in[4];
    const float* qw     = (const float*)d_in[5];
    const float* qbias  = (const float*)d_in[6];
    const float* kw     = (const float*)d_in[7];
    const float* kbias  = (const float*)d_in[8];
    const float* vw     = (const float*)d_in[9];
    const float* vbias  = (const float*)d_in[10];
    const float* ew     = (const float*)d_in[11];
    const float* ebias  = (const float*)d_in[12];
    const float* ln2_s  = (const float*)d_in[13];
    const float* ln2_b  = (const float*)d_in[14];
    const float* m1w    = (const float*)d_in[15];
    const float* m1b    = (const float*)d_in[16];
    const float* m2w    = (const float*)d_in[17];
    const float* m2b    = (const float*)d_in[18];
    const float* lnf_s  = (const float*)d_in[19];
    const float* lnf_b  = (const float*)d_in[20];
    const float* head_w = (const float*)d_in[21];
    const float* head_b = (const float*)d_in[22];
    float* out = (float*)d_out;

    const size_t act = (size_t)cMP * cEX;
    float* part = (float*)d_ws;                    // 255*8*256
    float* qkvb = part + 255 * 8 * 256;            // [11][2304]
    short* x    = (short*)(qkvb + cNBLK * cQKV);   // [4096][768] bf16 residual
    short* qkv  = x + act;                         // [4096][2304] bf16 (V region unused)
    short* vTr  = qkv + (size_t)cMP * cQKV;        // [768][4096] bf16
    short* h    = vTr + (size_t)cEX * cMP;         // [4096][768] bf16
    short* h2   = h + act;
    short* y    = h2 + act;
    short* u    = y + act;                         // [4096][3072] bf16
    short* wqkvT = u + (size_t)cMP * 4 * cEX;      // [11][2304][768]
    short* weT   = wqkvT + (size_t)cNBLK * cQKV * cEX;
    short* wm1T  = weT + (size_t)cNBLK * cEX * cEX;
    short* wm2T  = wm1T + (size_t)cNBLK * cEX * 4 * cEX;

    transpose_qkv<<<dim3(24, 24, 3 * cNBLK), 256, 0, stream>>>(qw, kw, vw, (bf16*)wqkvT);
    transpose_w<<<dim3(24, 24, cNBLK), 256, 0, stream>>>(ew, (bf16*)weT, cEX, cEX,
        (size_t)cEX * cEX, (size_t)cEX * cEX, 0);
    transpose_w<<<dim3(96, 24, cNBLK), 256, 0, stream>>>(m1w, (bf16*)wm1T, cEX, 4 * cEX,
        (size_t)cEX * 4 * cEX, (size_t)cEX * 4 * cEX, 0);
    transpose_w<<<dim3(24, 96, cNBLK), 256, 0, stream>>>(m2w, (bf16*)wm2T, 4 * cEX, cEX,
        (size_t)cEX * 4 * cEX, (size_t)cEX * 4 * cEX, 0);
    concat_bias<<<(cNBLK * cQKV + 255) / 256, 256, 0, stream>>>(qbias, kbias, vbias, qkvb);

    embed_kernel<<<cMP, 256, 0, stream>>>(idx, lin_w, lin_b, x);

    for (int blk = 0; blk < cNBLK; ++blk) {
        size_t bo = (size_t)blk * cEX;
        ln_wave<<<cMP / 4, 256, 0, stream>>>(x, ln1_s + bo, ln1_b + bo, h);
        // QKV fused: 128x96 tile -> grid 24x32 = 768 blocks (3/CU exact)
        gemm_db<4, 3, false, false, true, true><<<dim3(cQKV / 96, cMP / 128), 256, 0, stream>>>(
            h, wqkvT + (size_t)blk * cQKV * cEX, qkvb + (size_t)blk * cQKV, nullptr,
            qkv, vTr, cEX, cQKV);
        attn_mfma<<<8 * cNH * cB, 256, 0, stream>>>(qkv, vTr, (bf16*)y);
        // eproj: 64x96 tile -> grid 8x64 = 512 blocks (2/CU exact)
        gemm_db<2, 3, false, true, true, false><<<dim3(cEX / 96, cMP / 64), 256, 0, stream>>>(
            y, weT + (size_t)blk * cEX * cEX, ebias + bo, x, x, nullptr, cEX, cEX);
        ln_wave<<<cMP / 4, 256, 0, stream>>>(x, ln2_s + bo, ln2_b + bo, h2);
        // m1: 128x128 -> 24x32 = 768 blocks (3/CU exact)
        gemm_db<4, 4, true, false, true, false><<<dim3(4 * cEX / 128, cMP / 128), 256, 0, stream>>>(
            h2, wm1T + (size_t)blk * cEX * 4 * cEX, m1b + (size_t)blk * 4 * cEX, nullptr,
            u, nullptr, cEX, 4 * cEX);
        // m2: 64x96 -> 8x64 = 512 blocks (2/CU exact)
        gemm_db<2, 3, false, true, true, false><<<dim3(cEX / 96, cMP / 64), 256, 0, stream>>>(
            u, wm2T + (size_t)blk * cEX * 4 * cEX, m2b + bo, x, x, nullptr, 4 * cEX, cEX);
    }
    head_part_kernel<<<255, 256, 0, stream>>>(x, lnf_s, lnf_b, head_w, part);
    head_reduce_kernel<<<8, 256, 0, stream>>>(part, head_b, out);
}